// Round 4
// baseline (647.572 us; speedup 1.0000x reference)
//
#include <hip/hip_runtime.h>
#include <math.h>

// MoE FFN: top-2 of 8 experts + shared expert, H=1024, F=2048, N=4096.
// Round 4: (1) on-the-fly fp32->bf16 B-tile staging (weight cvt pass removed),
// (2) merged launches: cvtX, router, routing_misc(scan+lists+aux), 3 GEMMs,
// (3) dense work-list grids (no dummy blocks). MFMA tile math identical to R3.

#define H_DIM 1024
#define F_DIM 2048
#define E_NUM 8
#define EPSV 1e-9f
#define GU_MAX 104   // 32 shared + sum ceil(cnt_e/128) <= 71
#define DN_MAX 72

typedef __bf16 bf16x8 __attribute__((ext_vector_type(8)));
typedef float f32x4 __attribute__((ext_vector_type(4)));

#define MFMA16(a, b, c) __builtin_amdgcn_mfma_f32_16x16x32_bf16(a, b, c, 0, 0, 0)

__device__ __forceinline__ unsigned f2bf(float f) {
    unsigned u = __float_as_uint(f);
    return (u + 0x7FFFu + ((u >> 16) & 1u)) >> 16;  // RNE
}

__device__ __forceinline__ uint4 pack8(float4 a, float4 b) {
    uint4 o;
    o.x = f2bf(a.x) | (f2bf(a.y) << 16);
    o.y = f2bf(a.z) | (f2bf(a.w) << 16);
    o.z = f2bf(b.x) | (f2bf(b.y) << 16);
    o.w = f2bf(b.z) | (f2bf(b.w) << 16);
    return o;
}

// async global->LDS, 16B per lane; lds ptr must be wave-uniform
__device__ __forceinline__ void gload16(const ushort* g, ushort* l) {
    __builtin_amdgcn_global_load_lds(
        (__attribute__((address_space(1))) void*)(void*)const_cast<ushort*>(g),
        (__attribute__((address_space(3))) void*)l, 16, 0, 0);
}

// ---------------- fp32 -> bf16 conversion (X only) ----------------
__global__ void cvt_bf16_kernel(const float* __restrict__ src, ushort* __restrict__ dst, int n8) {
    int i = blockIdx.x * 256 + threadIdx.x;
    if (i >= n8) return;
    float4 a = ((const float4*)src)[2 * i];
    float4 b = ((const float4*)src)[2 * i + 1];
    ((uint4*)dst)[i] = pack8(a, b);
}

// ---------------- router: logits/softmax/top-2 (no atomics) ----------------
__global__ void router_logits_kernel(const float* __restrict__ X,
                                     const float* __restrict__ Wr, int N,
                                     float* __restrict__ P, float* __restrict__ zz,
                                     int* __restrict__ idxA, float* __restrict__ wA)
{
    int wave = threadIdx.x >> 6;
    int lane = threadIdx.x & 63;
    int n = blockIdx.x * 4 + wave;

    float acc[8];
#pragma unroll
    for (int e = 0; e < 8; e++) acc[e] = 0.f;
    const float* xr = X + (size_t)n * H_DIM;
    for (int h = lane; h < H_DIM; h += 64) {
        float xv = xr[h];
#pragma unroll
        for (int e = 0; e < 8; e++) acc[e] += xv * Wr[e * H_DIM + h];
    }
#pragma unroll
    for (int off = 32; off > 0; off >>= 1) {
#pragma unroll
        for (int e = 0; e < 8; e++) acc[e] += __shfl_xor(acc[e], off, 64);
    }

    if (lane == 0) {
        float m = acc[0];
#pragma unroll
        for (int e = 1; e < 8; e++) m = fmaxf(m, acc[e]);
        float p[8];
        float s = 0.f;
#pragma unroll
        for (int e = 0; e < 8; e++) { p[e] = expf(acc[e] - m); s += p[e]; }
        float z = m + logf(s);
        float inv = 1.f / s;
#pragma unroll
        for (int e = 0; e < 8; e++) p[e] *= inv;
        // strict > keeps lowest index on ties (matches lax.top_k)
        int t1 = 0; float b1 = p[0];
#pragma unroll
        for (int e = 1; e < 8; e++) if (p[e] > b1) { b1 = p[e]; t1 = e; }
        int t2 = (t1 == 0) ? 1 : 0; float b2 = p[t2];
#pragma unroll
        for (int e = 0; e < 8; e++) if (e != t1 && p[e] > b2) { b2 = p[e]; t2 = e; }

        float wsum = b1 + b2 + EPSV;
#pragma unroll
        for (int e = 0; e < 8; e++) P[(size_t)n * 8 + e] = p[e];
        zz[n] = z * z;
        idxA[2 * n] = t1; idxA[2 * n + 1] = t2;
        wA[2 * n] = b1 / wsum; wA[2 * n + 1] = b2 / wsum;
    }
}

// ------- routing misc: bucket scan + offsets + work-lists + aux (1 block) -------
__global__ void __launch_bounds__(1024)
routing_misc_kernel(const int* __restrict__ idxA, const float* __restrict__ P,
                    const float* __restrict__ zz, int N,
                    int* __restrict__ count, int* __restrict__ offsets,
                    int* __restrict__ posA, int* __restrict__ bucket_tok,
                    int* __restrict__ nlist, int* __restrict__ gu_list,
                    int* __restrict__ dn_list, float* __restrict__ aux_out)
{
    const int t = threadIdx.x;
    const int wave = t >> 6, lane = t & 63;
    __shared__ int wsum[16], wbase[16];
    __shared__ int run[8];
    __shared__ int ld[8];
    __shared__ float s_imp[1024];
    __shared__ float s_z[1024];
    if (t < 8) { run[t] = 0; ld[t] = 0; }
    __syncthreads();
    const unsigned long long lmask = (1ull << lane) - 1ull;

    for (int c0 = 0; c0 < 2 * N; c0 += 1024) {
        int i = c0 + t;
        int v = idxA[i];
#pragma unroll
        for (int e = 0; e < 8; e++) {
            unsigned long long mask = __ballot(v == e);
            int prefix = __popcll(mask & lmask);
            if (lane == 0) wsum[wave] = __popcll(mask);
            __syncthreads();
            if (t == 0) {
                int b = run[e];
                for (int w2 = 0; w2 < 16; w2++) { wbase[w2] = b; b += wsum[w2]; }
                run[e] = b;
            }
            __syncthreads();
            if (v == e) {
                int pos = wbase[wave] + prefix;
                posA[i] = pos;
                bucket_tok[(size_t)e * N + pos] = i >> 1;
            }
            if (lane == 0) {
                // even lanes <=> even i (c0, wave*64 both even): top-1 slots
                int c = __popcll(mask & 0x5555555555555555ull);
                if (c) atomicAdd(&ld[e], c);
            }
        }
    }

    // aux partial sums
    {
        int e = t & 7, n0 = t >> 3;
        float si = 0.f;
        for (int n = n0; n < N; n += 128) si += P[(size_t)n * 8 + e];
        s_imp[t] = si;
        float sz = 0.f;
        for (int n = t; n < N; n += 1024) sz += zz[n];
        s_z[t] = sz;
    }
    __syncthreads();
    for (int s = 512; s >= 8; s >>= 1) {
        if (t < s) s_imp[t] += s_imp[t + s];
        __syncthreads();
    }
    for (int s = 512; s >= 1; s >>= 1) {
        if (t < s) s_z[t] += s_z[t + s];
        __syncthreads();
    }

    if (t == 0) {
        int o = 0, ngu = 0, ndn = 0;
        for (int m = 0; m < N / 128; m++) gu_list[ngu++] = (8 << 8) | m;  // shared expert
        for (int e = 0; e < 8; e++) {
            offsets[e] = o; count[e] = run[e]; o += run[e];
            int mb = (run[e] + 127) >> 7;
            for (int m = 0; m < mb; m++) {
                gu_list[ngu++] = (e << 8) | m;
                dn_list[ndn++] = (e << 8) | m;
            }
        }
        nlist[0] = ngu; nlist[1] = ndn;
        float is = 0.f, ls = 0.f, impv[8], ldv[8];
        for (int e = 0; e < 8; e++) {
            impv[e] = s_imp[e]; ldv[e] = (float)ld[e];
            is += impv[e]; ls += ldv[e];
        }
        float lb = 0.f;
        for (int e = 0; e < 8; e++)
            lb += (impv[e] / (is + EPSV)) * (ldv[e] / (ls + EPSV));
        lb *= (float)E_NUM;
        aux_out[0] = 0.01f * lb + 0.001f * (s_z[0] / (float)N);
    }
}

// -------- gate+up for shared (e==8) AND routed experts, work-list grid --------
__global__ void __launch_bounds__(256, 2)
gemm_gateup_all(const ushort* __restrict__ Xb,
                const float* __restrict__ Wsg, const float* __restrict__ Wsu,
                const float* __restrict__ Weg, const float* __restrict__ Weu,
                const int* __restrict__ count, const int* __restrict__ offsets,
                const int* __restrict__ bucket_tok, const int* __restrict__ nlist,
                const int* __restrict__ gu_list,
                ushort* __restrict__ Hsh, ushort* __restrict__ He, int N)
{
    const int slot = blockIdx.y;
    if (slot >= nlist[0]) return;
    const int packed = gu_list[slot];
    const int e = packed >> 8;
    const int m0 = (packed & 255) * 128;
    const int f0 = blockIdx.x * 128;

    int cnt, base;
    const float *Wg, *Wu;
    if (e == 8) { cnt = N; base = 0; Wg = Wsg; Wu = Wsu; }
    else {
        cnt = count[e]; base = offsets[e];
        Wg = Weg + (size_t)e * F_DIM * H_DIM;
        Wu = Weu + (size_t)e * F_DIM * H_DIM;
    }

    __shared__ int rows[128];
    __shared__ ushort As[128 * 32], Bg[128 * 32], Bu[128 * 32];
    const int t = threadIdx.x;
    if (t < 128) {
        int r = m0 + t;
        rows[t] = (e == 8) ? r : bucket_tok[(size_t)e * N + (r < cnt ? r : cnt - 1)];
    }
    __syncthreads();

    const int w = t >> 6, lane = t & 63;
    const int sr = lane >> 2, sc = (lane & 3) * 8;
    const int r0 = 32 * w + sr, r1 = r0 + 16;
    const ushort* pa0 = Xb + (size_t)rows[r0] * H_DIM + sc;
    const ushort* pa1 = Xb + (size_t)rows[r1] * H_DIM + sc;
    const float* pg0 = Wg + (size_t)(f0 + r0) * H_DIM + sc;
    const float* pg1 = pg0 + (size_t)16 * H_DIM;
    const float* pu0 = Wu + (size_t)(f0 + r0) * H_DIM + sc;
    const float* pu1 = pu0 + (size_t)16 * H_DIM;
    ushort* lA0 = &As[w * 1024]; ushort* lA1 = lA0 + 512;
    ushort* bgw = &Bg[w * 1024];
    ushort* buw = &Bu[w * 1024];

    const int wm = w & 1, wn = w >> 1;
    const int lm = lane & 15, quad = lane >> 4;
    const int aoff = (wm * 64 + lm) * 32 + quad * 8;
    const int boff = (wn * 64 + lm) * 32 + quad * 8;

    f32x4 zero4 = {0.f, 0.f, 0.f, 0.f};
    f32x4 accg[4][4], accu[4][4];
#pragma unroll
    for (int i = 0; i < 4; i++)
#pragma unroll
        for (int j = 0; j < 4; j++) { accg[i][j] = zero4; accu[i][j] = zero4; }

    for (int k0 = 0; k0 < H_DIM; k0 += 32) {
        float4 ga0 = *(const float4*)(pg0 + k0), ga1 = *(const float4*)(pg0 + k0 + 4);
        float4 gb0 = *(const float4*)(pg1 + k0), gb1 = *(const float4*)(pg1 + k0 + 4);
        float4 ua0 = *(const float4*)(pu0 + k0), ua1 = *(const float4*)(pu0 + k0 + 4);
        float4 ub0 = *(const float4*)(pu1 + k0), ub1 = *(const float4*)(pu1 + k0 + 4);
        gload16(pa0 + k0, lA0); gload16(pa1 + k0, lA1);
        *(uint4*)&bgw[lane * 8]       = pack8(ga0, ga1);
        *(uint4*)&bgw[512 + lane * 8] = pack8(gb0, gb1);
        *(uint4*)&buw[lane * 8]       = pack8(ua0, ua1);
        *(uint4*)&buw[512 + lane * 8] = pack8(ub0, ub1);
        __syncthreads();
        bf16x8 bgf[4], buf_[4];
#pragma unroll
        for (int j = 0; j < 4; j++) {
            bgf[j]  = *(const bf16x8*)&Bg[boff + j * 16 * 32];
            buf_[j] = *(const bf16x8*)&Bu[boff + j * 16 * 32];
        }
#pragma unroll
        for (int i = 0; i < 4; i++) {
            bf16x8 a = *(const bf16x8*)&As[aoff + i * 16 * 32];
#pragma unroll
            for (int j = 0; j < 4; j++) {
                accg[i][j] = MFMA16(a, bgf[j], accg[i][j]);
                accu[i][j] = MFMA16(a, buf_[j], accu[i][j]);
            }
        }
        __syncthreads();
    }

    ushort* db = (e == 8) ? (Hsh + (size_t)m0 * F_DIM) : (He + (size_t)(base + m0) * F_DIM);
#pragma unroll
    for (int i = 0; i < 4; i++)
#pragma unroll
        for (int j = 0; j < 4; j++) {
            int rb = wm * 64 + i * 16 + quad * 4;
            int col = f0 + wn * 64 + j * 16 + lm;
#pragma unroll
            for (int r = 0; r < 4; r++) {
                int rl = rb + r;
                if (m0 + rl < cnt) {
                    float g = accg[i][j][r], u = accu[i][j][r];
                    float hv = g / (1.f + __expf(-g)) * u;
                    db[(size_t)rl * F_DIM + col] = (ushort)f2bf(hv);
                }
            }
        }
}

// ---------------- routed experts down proj -> R fp32 (work-list) ----------------
__global__ void __launch_bounds__(256, 2)
gemm_ex_down(const ushort* __restrict__ He, const float* __restrict__ Wed,
             const int* __restrict__ count, const int* __restrict__ offsets,
             const int* __restrict__ nlist, const int* __restrict__ dn_list,
             float* __restrict__ R)
{
    const int slot = blockIdx.y;
    if (slot >= nlist[1]) return;
    const int packed = dn_list[slot];
    const int e = packed >> 8;
    const int m0 = (packed & 255) * 128;
    const int h0 = blockIdx.x * 128;
    const int cnt = count[e];
    const int base = offsets[e];
    const float* Wd = Wed + (size_t)e * H_DIM * F_DIM;

    __shared__ ushort As[128 * 32], Bs[128 * 32];
    const int t = threadIdx.x;
    const int w = t >> 6, lane = t & 63;
    const int sr = lane >> 2, sc = (lane & 3) * 8;
    const int r0 = 32 * w + sr, r1 = r0 + 16;
    int ar0 = m0 + r0; if (ar0 >= cnt) ar0 = cnt - 1;
    int ar1 = m0 + r1; if (ar1 >= cnt) ar1 = cnt - 1;
    const ushort* pa0 = He + (size_t)(base + ar0) * F_DIM + sc;
    const ushort* pa1 = He + (size_t)(base + ar1) * F_DIM + sc;
    const float* pb0 = Wd + (size_t)(h0 + r0) * F_DIM + sc;
    const float* pb1 = pb0 + (size_t)16 * F_DIM;
    ushort* lA0 = &As[w * 1024]; ushort* lA1 = lA0 + 512;
    ushort* bw = &Bs[w * 1024];

    const int wm = w & 1, wn = w >> 1;
    const int lm = lane & 15, quad = lane >> 4;
    const int aoff = (wm * 64 + lm) * 32 + quad * 8;
    const int boff = (wn * 64 + lm) * 32 + quad * 8;

    f32x4 zero4 = {0.f, 0.f, 0.f, 0.f};
    f32x4 acc[4][4];
#pragma unroll
    for (int i = 0; i < 4; i++)
#pragma unroll
        for (int j = 0; j < 4; j++) acc[i][j] = zero4;

    for (int k0 = 0; k0 < F_DIM; k0 += 32) {
        float4 b0 = *(const float4*)(pb0 + k0), b1 = *(const float4*)(pb0 + k0 + 4);
        float4 b2 = *(const float4*)(pb1 + k0), b3 = *(const float4*)(pb1 + k0 + 4);
        gload16(pa0 + k0, lA0); gload16(pa1 + k0, lA1);
        *(uint4*)&bw[lane * 8]       = pack8(b0, b1);
        *(uint4*)&bw[512 + lane * 8] = pack8(b2, b3);
        __syncthreads();
        bf16x8 bf_[4];
#pragma unroll
        for (int j = 0; j < 4; j++) bf_[j] = *(const bf16x8*)&Bs[boff + j * 16 * 32];
#pragma unroll
        for (int i = 0; i < 4; i++) {
            bf16x8 a = *(const bf16x8*)&As[aoff + i * 16 * 32];
#pragma unroll
            for (int j = 0; j < 4; j++) acc[i][j] = MFMA16(a, bf_[j], acc[i][j]);
        }
        __syncthreads();
    }
#pragma unroll
    for (int i = 0; i < 4; i++)
#pragma unroll
        for (int j = 0; j < 4; j++) {
            int rb = wm * 64 + i * 16 + quad * 4;
            int col = h0 + wn * 64 + j * 16 + lm;
#pragma unroll
            for (int r = 0; r < 4; r++) {
                int rl = rb + r;
                if (m0 + rl < cnt)
                    R[(size_t)(base + m0 + rl) * H_DIM + col] = acc[i][j][r];
            }
        }
}

// ---------------- shared down + top-2 combine ----------------
__global__ void __launch_bounds__(256, 2)
gemm_sh_down_combine(const ushort* __restrict__ Hsh, const float* __restrict__ Wsd,
                     const float* __restrict__ R, const int* __restrict__ idxA,
                     const int* __restrict__ posA, const float* __restrict__ wA,
                     const int* __restrict__ offsets, float* __restrict__ Y)
{
    const int m0 = blockIdx.y * 128;
    const int h0 = blockIdx.x * 128;

    __shared__ ushort As[128 * 32], Bs[128 * 32];
    __shared__ int r0s[128], r1s[128];
    __shared__ float w0s[128], w1s[128];
    const int t = threadIdx.x;
    if (t < 128) {
        int n = m0 + t;
        int e0 = idxA[2 * n], e1 = idxA[2 * n + 1];
        r0s[t] = offsets[e0] + posA[2 * n];
        r1s[t] = offsets[e1] + posA[2 * n + 1];
        w0s[t] = wA[2 * n];
        w1s[t] = wA[2 * n + 1];
    }

    const int w = t >> 6, lane = t & 63;
    const int sr = lane >> 2, sc = (lane & 3) * 8;
    const int r0 = 32 * w + sr, r1 = r0 + 16;
    const ushort* pa0 = Hsh + (size_t)(m0 + r0) * F_DIM + sc;
    const ushort* pa1 = Hsh + (size_t)(m0 + r1) * F_DIM + sc;
    const float* pb0 = Wsd + (size_t)(h0 + r0) * F_DIM + sc;
    const float* pb1 = pb0 + (size_t)16 * F_DIM;
    ushort* lA0 = &As[w * 1024]; ushort* lA1 = lA0 + 512;
    ushort* bw = &Bs[w * 1024];

    const int wm = w & 1, wn = w >> 1;
    const int lm = lane & 15, quad = lane >> 4;
    const int aoff = (wm * 64 + lm) * 32 + quad * 8;
    const int boff = (wn * 64 + lm) * 32 + quad * 8;

    f32x4 zero4 = {0.f, 0.f, 0.f, 0.f};
    f32x4 acc[4][4];
#pragma unroll
    for (int i = 0; i < 4; i++)
#pragma unroll
        for (int j = 0; j < 4; j++) acc[i][j] = zero4;

    for (int k0 = 0; k0 < F_DIM; k0 += 32) {
        float4 b0 = *(const float4*)(pb0 + k0), b1 = *(const float4*)(pb0 + k0 + 4);
        float4 b2 = *(const float4*)(pb1 + k0), b3 = *(const float4*)(pb1 + k0 + 4);
        gload16(pa0 + k0, lA0); gload16(pa1 + k0, lA1);
        *(uint4*)&bw[lane * 8]       = pack8(b0, b1);
        *(uint4*)&bw[512 + lane * 8] = pack8(b2, b3);
        __syncthreads();
        bf16x8 bf_[4];
#pragma unroll
        for (int j = 0; j < 4; j++) bf_[j] = *(const bf16x8*)&Bs[boff + j * 16 * 32];
#pragma unroll
        for (int i = 0; i < 4; i++) {
            bf16x8 a = *(const bf16x8*)&As[aoff + i * 16 * 32];
#pragma unroll
            for (int j = 0; j < 4; j++) acc[i][j] = MFMA16(a, bf_[j], acc[i][j]);
        }
        __syncthreads();
    }
#pragma unroll
    for (int i = 0; i < 4; i++)
#pragma unroll
        for (int j = 0; j < 4; j++) {
            int rb = wm * 64 + i * 16 + quad * 4;
            int col = h0 + wn * 64 + j * 16 + lm;
#pragma unroll
            for (int r = 0; r < 4; r++) {
                int rl = rb + r;
                float v = acc[i][j][r]
                        + w0s[rl] * R[(size_t)r0s[rl] * H_DIM + col]
                        + w1s[rl] * R[(size_t)r1s[rl] * H_DIM + col];
                Y[(size_t)(m0 + rl) * H_DIM + col] = v;
            }
        }
}

extern "C" void kernel_launch(void* const* d_in, const int* in_sizes, int n_in,
                              void* d_out, int out_size, void* d_ws, size_t ws_size,
                              hipStream_t stream)
{
    const float* x         = (const float*)d_in[0];
    const float* w_router  = (const float*)d_in[1];
    const float* w_sh_gate = (const float*)d_in[2];
    const float* w_sh_up   = (const float*)d_in[3];
    const float* w_sh_down = (const float*)d_in[4];
    const float* w_e_gate  = (const float*)d_in[5];
    const float* w_e_up    = (const float*)d_in[6];
    const float* w_e_down  = (const float*)d_in[7];
    float* out = (float*)d_out;
    int N = in_sizes[0] / H_DIM;  // 4096

    char* ws = (char*)d_ws;
    int* count   = (int*)(ws + 0);
    int* offsets = (int*)(ws + 32);
    int* nlist   = (int*)(ws + 64);
    int* gu_list = (int*)(ws + 128);
    int* dn_list = (int*)(ws + 640);
    size_t off = 1024;
    int*   idxA = (int*)(ws + off);  off += (size_t)N * 2 * 4;
    int*   posA = (int*)(ws + off);  off += (size_t)N * 2 * 4;
    float* wA   = (float*)(ws + off); off += (size_t)N * 2 * 4;
    int*   bucket_tok = (int*)(ws + off); off += (size_t)E_NUM * N * 4;
    float* P    = (float*)(ws + off); off += (size_t)N * 8 * 4;
    float* zz   = (float*)(ws + off); off += (size_t)N * 4;
    off = (off + 255) & ~(size_t)255;
    ushort* Xb  = (ushort*)(ws + off); off += (size_t)N * H_DIM * 2;
    ushort* Hsh = (ushort*)(ws + off); off += (size_t)N * F_DIM * 2;
    ushort* He  = (ushort*)(ws + off); off += (size_t)2 * N * F_DIM * 2;
    float*  R   = (float*)(ws + off);  off += (size_t)2 * N * H_DIM * 4;

    int n8 = N * H_DIM / 8;
    cvt_bf16_kernel<<<(n8 + 255) / 256, 256, 0, stream>>>(x, Xb, n8);
    router_logits_kernel<<<N / 4, 256, 0, stream>>>(x, w_router, N, P, zz, idxA, wA);
    routing_misc_kernel<<<1, 1024, 0, stream>>>(idxA, P, zz, N, count, offsets,
                                                posA, bucket_tok, nlist, gu_list,
                                                dn_list, out + (size_t)N * H_DIM);
    gemm_gateup_all<<<dim3(F_DIM / 128, GU_MAX), 256, 0, stream>>>(
        Xb, w_sh_gate, w_sh_up, w_e_gate, w_e_up,
        count, offsets, bucket_tok, nlist, gu_list, Hsh, He, N);
    gemm_ex_down<<<dim3(H_DIM / 128, DN_MAX), 256, 0, stream>>>(
        He, w_e_down, count, offsets, nlist, dn_list, R);
    gemm_sh_down_combine<<<dim3(H_DIM / 128, N / 128), 256, 0, stream>>>(
        Hsh, w_sh_down, R, idxA, posA, wA, offsets, out);
}